// Round 6
// baseline (463.719 us; speedup 1.0000x reference)
//
#include <hip/hip_runtime.h>
#include <hip/hip_bf16.h>

// WindowAttentionRPB v6, MI355X gfx950. Three dispatches:
//  preconv: weights->bf16 (scale folded into Wq), rpb gather, mask permute.
//  K1 attn: ONE WAVE per (window,head). 16384 blocks x 64 thr, 0 barriers,
//           8K static LDS (vT 4K + P 4K). Q/K stay in registers (shared
//           in-lane d-permutation cancels in S = Q K^T). Writes attn-out
//           bf16 into d_out row t bytes [t*1024, t*1024+512).
//  K2 proj: block = 64 toks (1 window) x 256 oc, 4 waves. Reads the bf16
//           attn-out rows it owns, one barrier, overwrites same rows fp32.
// XCD swizzle on both: block%8 picks XCD; remap so each XCD owns a
// contiguous window range (K1: windows c*256..+256; K2 same).

#define TOK 64
#define CDIM 256

typedef __attribute__((ext_vector_type(8))) short short8;
typedef __attribute__((ext_vector_type(4))) float f32x4;
typedef __attribute__((ext_vector_type(4))) float float4_t;

__device__ __forceinline__ short f2bf(float f) {
  union { float f; unsigned u; } v; v.f = f;
  unsigned r = v.u + 0x7FFFu + ((v.u >> 16) & 1u);
  return (short)(r >> 16);
}

__device__ __forceinline__ unsigned cvt2(float a, float b) {
  union { __hip_bfloat162 h; unsigned u; } v;
  v.h = __float22bfloat162_rn(make_float2(a, b));
  return v.u;
}

__device__ __forceinline__ short8 pack88(f32x4 lo, f32x4 hi) {
  union { short8 s; unsigned u[4]; } r;
  r.u[0] = cvt2(lo[0], lo[1]);
  r.u[1] = cvt2(lo[2], lo[3]);
  r.u[2] = cvt2(hi[0], hi[1]);
  r.u[3] = cvt2(hi[2], hi[3]);
  return r.s;
}

__global__ void preconv_kernel(const float* __restrict__ qkv_w,
                               const float* __restrict__ proj_w,
                               const float* __restrict__ rpb_table,
                               const int* __restrict__ rpb_index,
                               const float* __restrict__ mask,
                               short* __restrict__ wqkv,
                               short* __restrict__ wproj,
                               float* __restrict__ rpbT,
                               float* __restrict__ maskT) {
  int idx = blockIdx.x * blockDim.x + threadIdx.x;
  const float scale = 0.17677669529663687f; // 1/sqrt(32), folded into Wq
  const int NW1 = 768 * 256;
  const int NW2 = NW1 + 256 * 256;
  const int NW3 = NW2 + 8 * 64 * 64;
  const int NW4 = NW3 + 64 * 64 * 64;
  if (idx < NW1) {
    float v = qkv_w[idx];
    if (idx < 256 * 256) v *= scale;
    wqkv[idx] = f2bf(v);
  } else if (idx < NW2) {
    int i = idx - NW1;
    wproj[i] = f2bf(proj_w[i]);
  } else if (idx < NW3) {
    int i = idx - NW2;             // [h][qtok][ll*4+ni]
    int h = i >> 12;
    int pos = i & 4095;
    int qtok = pos >> 6;
    int t = pos & 63;
    int llv = t >> 2, ni = t & 3;
    int kt = ni * 16 + llv;
    rpbT[i] = rpb_table[rpb_index[qtok * 64 + kt] * 8 + h];
  } else if (idx < NW4) {
    int i = idx - NW3;             // [win][qtok][ll*4+ni]
    int win = i >> 12;
    int pos = i & 4095;
    int qtok = pos >> 6;
    int t = pos & 63;
    int llv = t >> 2, ni = t & 3;
    int kt = ni * 16 + llv;
    maskT[i] = mask[win * 4096 + qtok * 64 + kt];
  }
}

// ---------------- K1: one wave per (window, head) ----------------
__global__ void __launch_bounds__(64, 3) attn_kernel(
    const float* __restrict__ x, const float* __restrict__ qkv_b,
    const short* __restrict__ wqkv,
    const float* __restrict__ rpbT, const float* __restrict__ maskT,
    float* __restrict__ out) {
  __shared__ char smem[8192];          // [0,4K) vT, [4K,8K) P-chunk
  const int bid = blockIdx.x;
  const int sid = (bid & 7) * 2048 + (bid >> 3);  // XCD-contiguous windows
  const int w = sid >> 3;              // window 0..2047
  const int h = sid & 7;               // head
  const int lane = threadIdx.x & 63;
  const int lg = lane >> 4;
  const int ll = lane & 15;
  const float scale = 0.17677669529663687f;

  const float* xb = x + (size_t)w * TOK * CDIM;

  // ---- loop A: Q,K transposed form  C[c][tok] = W[c][:] . x[tok][:]
  f32x4 aqk[4][4] = {};
#pragma unroll
  for (int ks = 0; ks < 8; ++ks) {
    const int k0 = ks * 32 + lg * 8;
    short8 xf[4];
#pragma unroll
    for (int ni = 0; ni < 4; ++ni) {
      const float* px = xb + (ni * 16 + ll) * 256 + k0;
      xf[ni] = pack88(*reinterpret_cast<const float4_t*>(px),
                      *reinterpret_cast<const float4_t*>(px + 4));
    }
#pragma unroll
    for (int j = 0; j < 4; ++j) {
      const int cbase = (j >> 1) * 256 + h * 32 + (j & 1) * 16;
      short8 wf = *reinterpret_cast<const short8*>(wqkv + (cbase + ll) * 256 + k0);
#pragma unroll
      for (int ni = 0; ni < 4; ++ni)
        aqk[ni][j] = __builtin_amdgcn_mfma_f32_16x16x32_bf16(wf, xf[ni], aqk[ni][j], 0, 0, 0);
    }
  }
  f32x4 bj[4];
#pragma unroll
  for (int j = 0; j < 4; ++j) {
    float4_t t = *reinterpret_cast<const float4_t*>(
        qkv_b + (j >> 1) * 256 + h * 32 + (j & 1) * 16 + lg * 4);
    bj[j] = (j < 2) ? t * scale : t;
  }
  short8 aq[4], bk[4];
#pragma unroll
  for (int ni = 0; ni < 4; ++ni) {
    aq[ni] = pack88(aqk[ni][0] + bj[0], aqk[ni][1] + bj[1]);
    bk[ni] = pack88(aqk[ni][2] + bj[2], aqk[ni][3] + bj[3]);
  }

  // ---- loop B: V normal form  C[tok][d] = x[tok][:] . Wv[d][:]
  f32x4 av[4][2] = {};
#pragma unroll
  for (int ks = 0; ks < 8; ++ks) {
    const int k0 = ks * 32 + lg * 8;
    short8 xf[4];
#pragma unroll
    for (int mi = 0; mi < 4; ++mi) {
      const float* px = xb + (mi * 16 + ll) * 256 + k0;
      xf[mi] = pack88(*reinterpret_cast<const float4_t*>(px),
                      *reinterpret_cast<const float4_t*>(px + 4));
    }
#pragma unroll
    for (int hf = 0; hf < 2; ++hf) {
      short8 wfv = *reinterpret_cast<const short8*>(
          wqkv + (512 + h * 32 + hf * 16 + ll) * 256 + k0);
#pragma unroll
      for (int mi = 0; mi < 4; ++mi)
        av[mi][hf] = __builtin_amdgcn_mfma_f32_16x16x32_bf16(xf[mi], wfv, av[mi][hf], 0, 0, 0);
    }
  }
  // vT [32 d][64 tok] bf16 at 0 (rows 128B, XOR swz (d&7)<<4), packed b64
#pragma unroll
  for (int hf = 0; hf < 2; ++hf) {
    float bb = qkv_b[512 + h * 32 + hf * 16 + ll];
    int d = hf * 16 + ll;
#pragma unroll
    for (int mi = 0; mi < 4; ++mi) {
      f32x4 v = av[mi][hf];
      int tok0 = 16 * mi + lg * 4;
      union { unsigned long long q; unsigned u[2]; } pk;
      pk.u[0] = cvt2(v[0] + bb, v[1] + bb);
      pk.u[1] = cvt2(v[2] + bb, v[3] + bb);
      *reinterpret_cast<unsigned long long*>(
          smem + d * 128 + ((tok0 * 2) ^ ((d & 7) << 4))) = pk.q;
    }
  }

  // ---- S = Q K^T + rpb + mask
  f32x4 sa[4][4];
  {
    f32x4 z{0.0f, 0.0f, 0.0f, 0.0f};
#pragma unroll
    for (int mi = 0; mi < 4; ++mi)
#pragma unroll
      for (int ni = 0; ni < 4; ++ni)
        sa[mi][ni] = __builtin_amdgcn_mfma_f32_16x16x32_bf16(aq[mi], bk[ni], z, 0, 0, 0);
    const float4_t* rpT4 = reinterpret_cast<const float4_t*>(rpbT) + h * 1024;
    const float4_t* mkT4 = reinterpret_cast<const float4_t*>(maskT) + (w & 63) * 1024;
#pragma unroll
    for (int mi = 0; mi < 4; ++mi)
#pragma unroll
      for (int r = 0; r < 4; ++r) {
        int qtok = mi * 16 + lg * 4 + r;
        float4_t f = rpT4[qtok * 16 + ll];
        float4_t g = mkT4[qtok * 16 + ll];
#pragma unroll
        for (int ni = 0; ni < 4; ++ni)
          sa[mi][ni][r] += f[ni] + g[ni];
      }
  }

  // ---- softmax over k-cols (row's 64 cols live in one 16-lane group)
  float rinv[4][4];
#pragma unroll
  for (int mi = 0; mi < 4; ++mi)
#pragma unroll
    for (int r = 0; r < 4; ++r) {
      float m = sa[mi][0][r];
#pragma unroll
      for (int ni = 1; ni < 4; ++ni) m = fmaxf(m, sa[mi][ni][r]);
      for (int d = 1; d < 16; d <<= 1) m = fmaxf(m, __shfl_xor(m, d));
      float sum = 0.f;
#pragma unroll
      for (int ni = 0; ni < 4; ++ni) {
        float e = __expf(sa[mi][ni][r] - m);
        sa[mi][ni][r] = e;
        sum += e;
      }
      for (int d = 1; d < 16; d <<= 1) sum += __shfl_xor(sum, d);
      rinv[mi][r] = 1.0f / sum;
    }

  // ---- PV as O^T = V^T P^T in two 32-kt chunks (P at 4K)
  f32x4 oa[2][4] = {};
#pragma unroll
  for (int ks = 0; ks < 2; ++ks) {
#pragma unroll
    for (int mi = 0; mi < 4; ++mi)
#pragma unroll
      for (int nio = 0; nio < 2; ++nio) {
        int ni = 2 * ks + nio;
        unsigned u01 = cvt2(sa[mi][ni][0] * rinv[mi][0], sa[mi][ni][1] * rinv[mi][1]);
        unsigned u23 = cvt2(sa[mi][ni][2] * rinv[mi][2], sa[mi][ni][3] * rinv[mi][3]);
        int col2 = (nio * 16 + ll) * 2;
        int qt0 = 16 * mi + lg * 4;
        *reinterpret_cast<short*>(smem + 4096 + (qt0 + 0) * 64 + (col2 ^ (((qt0 + 0) & 3) << 4))) = (short)(u01);
        *reinterpret_cast<short*>(smem + 4096 + (qt0 + 1) * 64 + (col2 ^ (((qt0 + 1) & 3) << 4))) = (short)(u01 >> 16);
        *reinterpret_cast<short*>(smem + 4096 + (qt0 + 2) * 64 + (col2 ^ (((qt0 + 2) & 3) << 4))) = (short)(u23);
        *reinterpret_cast<short*>(smem + 4096 + (qt0 + 3) * 64 + (col2 ^ (((qt0 + 3) & 3) << 4))) = (short)(u23 >> 16);
      }
    short8 pf[4], vf[2];
#pragma unroll
    for (int ni = 0; ni < 4; ++ni) {
      int qt = ll + 16 * ni;
      pf[ni] = *reinterpret_cast<const short8*>(
          smem + 4096 + qt * 64 + ((lg * 16) ^ ((qt & 3) << 4)));
    }
#pragma unroll
    for (int hf = 0; hf < 2; ++hf) {
      int d = ll + 16 * hf;
      vf[hf] = *reinterpret_cast<const short8*>(
          smem + d * 128 + (((ks * 32 + lg * 8) * 2) ^ ((d & 7) << 4)));
    }
#pragma unroll
    for (int hf = 0; hf < 2; ++hf)
#pragma unroll
      for (int ni = 0; ni < 4; ++ni)
        oa[hf][ni] = __builtin_amdgcn_mfma_f32_16x16x32_bf16(vf[hf], pf[ni], oa[hf][ni], 0, 0, 0);
  }

  // ---- store attn-out bf16 into d_out: row qt bytes [qt*1024, +512)
  char* ob = reinterpret_cast<char*>(out) + (size_t)w * TOK * 1024;
#pragma unroll
  for (int hf = 0; hf < 2; ++hf)
#pragma unroll
    for (int ni = 0; ni < 4; ++ni) {
      int qt = ll + 16 * ni;
      union { unsigned long long q; unsigned u[2]; } pk;
      pk.u[0] = cvt2(oa[hf][ni][0], oa[hf][ni][1]);
      pk.u[1] = cvt2(oa[hf][ni][2], oa[hf][ni][3]);
      *reinterpret_cast<unsigned long long*>(
          ob + (size_t)qt * 1024 + h * 64 + hf * 32 + lg * 8) = pk.q;
    }
}

// ---------------- K2: proj over one window (64 toks) ----------------
__global__ void __launch_bounds__(256, 3) proj_kernel(
    const short* __restrict__ wproj, const float* __restrict__ proj_b,
    float* __restrict__ out) {
  const int bid = blockIdx.x;
  const int t = (bid & 7) * 256 + (bid >> 3);   // window, XCD-matched to K1
  const int wv = threadIdx.x >> 6;              // oc quarter (64 oc)
  const int lane = threadIdx.x & 63;
  const int lg = lane >> 4;
  const int ll = lane & 15;
  const char* ab = reinterpret_cast<const char*>(out) + (size_t)t * TOK * 1024;

  // C[oc][tok] = Wp[oc][:] . attnout[tok][:]
  f32x4 pa[4][4] = {};   // [jj: oc 16-tile][ni: tok 16-tile]
#pragma unroll
  for (int ks = 0; ks < 8; ++ks) {
    const int k0 = ks * 32 + lg * 8;
    short8 af[4];
#pragma unroll
    for (int ni = 0; ni < 4; ++ni)
      af[ni] = *reinterpret_cast<const short8*>(
          ab + (size_t)(ni * 16 + ll) * 1024 + k0 * 2);
#pragma unroll
    for (int jj = 0; jj < 4; ++jj) {
      short8 wf = *reinterpret_cast<const short8*>(
          wproj + (wv * 64 + jj * 16 + ll) * 256 + k0);
#pragma unroll
      for (int ni = 0; ni < 4; ++ni)
        pa[jj][ni] = __builtin_amdgcn_mfma_f32_16x16x32_bf16(wf, af[ni], pa[jj][ni], 0, 0, 0);
    }
  }
  __syncthreads();  // all waves' attn-out reads done before overwriting rows

  float* op = out + (size_t)t * TOK * CDIM;
#pragma unroll
  for (int jj = 0; jj < 4; ++jj) {
    int oc0 = wv * 64 + jj * 16 + lg * 4;
    float4_t pb = *reinterpret_cast<const float4_t*>(proj_b + oc0);
#pragma unroll
    for (int ni = 0; ni < 4; ++ni) {
      f32x4 v = pa[jj][ni] + pb;
      *reinterpret_cast<float4_t*>(op + (ni * 16 + ll) * 256 + oc0) = v;
    }
  }
}

extern "C" void kernel_launch(void* const* d_in, const int* in_sizes, int n_in,
                              void* d_out, int out_size, void* d_ws, size_t ws_size,
                              hipStream_t stream) {
  const float* x        = (const float*)d_in[0];
  const float* mask     = (const float*)d_in[1];
  const float* qkv_w    = (const float*)d_in[2];
  const float* qkv_b    = (const float*)d_in[3];
  const float* proj_w   = (const float*)d_in[4];
  const float* proj_b   = (const float*)d_in[5];
  const float* rpb_tab  = (const float*)d_in[6];
  const int*   rpb_idx  = (const int*)d_in[7];
  float* out = (float*)d_out;

  short* wqkv  = (short*)d_ws;                  // 196608 shorts
  short* wproj = wqkv + 768 * 256;              // 65536 shorts
  float* rpbT  = (float*)(wproj + 256 * 256);   // 32768 floats
  float* maskT = rpbT + 8 * 64 * 64;            // 262144 floats

  int total = 768 * 256 + 256 * 256 + 8 * 64 * 64 + 64 * 64 * 64;
  preconv_kernel<<<(total + 255) / 256, 256, 0, stream>>>(
      qkv_w, proj_w, rpb_tab, rpb_idx, mask, wqkv, wproj, rpbT, maskT);

  int B = in_sizes[0] / (TOK * CDIM);  // 2048
  attn_kernel<<<B * 8, 64, 0, stream>>>(x, qkv_b, wqkv, rpbT, maskT, out);
  proj_kernel<<<B, 256, 0, stream>>>(wproj, proj_b, out);
}